// Round 6
// baseline (64.257 us; speedup 1.0000x reference)
//
#include <hip/hip_runtime.h>
#include <math.h>

#define B_ 512
#define C_ 512
#define D_ 512
#define LDK 520   // LDS row stride in bf16 elems: 512 + 8 pad (row-to-row quad shift = 1 -> uniform banks)

typedef __attribute__((ext_vector_type(8))) short s8v;   // 8 bf16 = 4 VGPR (MFMA A/B frag)
typedef __attribute__((ext_vector_type(4))) float f4v;   // MFMA acc

__device__ __forceinline__ float compute_c_dev(float rc) {
    float sp = fmaxf(rc, 0.0f) + log1pf(expf(-fabsf(rc)));  // stable softplus (once/thread)
    float c = sp + 1e-6f;
    return fminf(fmaxf(c, 1e-4f), 1e4f);
}

__device__ __forceinline__ unsigned short f2bf(float f) {  // RNE fp32 -> bf16
    unsigned u = __float_as_uint(f);
    u += 0x7FFFu + ((u >> 16) & 1u);
    return (unsigned short)(u >> 16);
}

// tanh(x) for x>0 via fast exp: tanh = 1 - 2/(e^{2x}+1)
__device__ __forceinline__ float fast_tanh_pos(float x) {
    float e = __expf(2.0f * x);
    return 1.0f - __fdividef(2.0f, e + 1.0f);
}

__device__ __forceinline__ float dist_val(float zp, float x2, float y2,
                                          float c, float scc, float inv_sc) {
    float xy = -zp;                               // <x,p>, x = -z
    float two_cxy = 2.0f * c * xy;
    float a = 1.0f + two_cxy + c * y2;
    float b = 1.0f - c * x2;
    float den = fmaxf(1.0f + two_cxy + c * c * x2 * y2, 1e-15f);
    float num2 = a * a * x2 + 2.0f * a * b * xy + b * b * y2;  // ||a*x + b*p||^2 exactly
    float mn = __fdividef(sqrtf(fmaxf(num2, 0.0f)), den);
    float t = fminf(scc * mn, 1.0f - 1e-7f);      // t >= 0: only upper clip binds
    return -inv_sc * __logf(__fdividef(1.0f + t, 1.0f - t));  // -(2/sc)*artanh(t)
}

// 512 threads = 8 waves. Phase 1: wave w preps 8 rows IN PARALLEL (8 lanes/row,
// 64 elems/lane): 3-shfl group reduce + one tanh chain per wave. Waves 0-3: feat
// rows, waves 4-7: proto rows. Phase 2: split-K MFMA (wave = quadrant x K-half),
// halves combined via LDS. 8 waves/CU = 2/SIMD.
__global__ __launch_bounds__(512) void fused_kernel(
    const float* __restrict__ feats, const float* __restrict__ protos,
    const float* __restrict__ raw_c, float* __restrict__ out)
{
    __shared__ short zs[32 * LDK];   // bf16 A tile (feats after expmap0)
    __shared__ short ps[32 * LDK];   // bf16 B tile (protos after expmap0)
    __shared__ float x2s[32];
    __shared__ float y2s[32];
    __shared__ f4v  accbuf[256];     // K-half partial sums (4 KB)

    const int t    = threadIdx.x;
    const int lane = t & 63;
    const int w    = t >> 6;              // wave 0..7
    const int row0 = blockIdx.y * 32;
    const int col0 = blockIdx.x * 32;

    const float c      = compute_c_dev(raw_c[0]);
    const float scc    = sqrtf(c);
    const float inv_sc = 1.0f / scc;

    // ---- phase 1: expmap0 both tiles -> LDS (bf16), squared norms -> x2s/y2s ----
    {
        const bool isB = (w >= 4);
        const int  wl  = w & 3;           // 0..3
        const int  g   = lane >> 3;       // row within batch: 0..7
        const int  le  = lane & 7;        // elem-lane within row
        const int  rt  = 8 * wl + g;      // row in tile: 0..31
        const float* srcRow = isB ? (protos + (size_t)(col0 + rt) * D_)
                                  : (feats  + (size_t)(row0 + rt) * D_);
        short* dst = isB ? ps : zs;
        float* sqv = isB ? y2s : x2s;

        // lane owns f32 elems [le*64, le*64+64) of its row (16 contiguous float4)
        const float4* s4p = (const float4*)srcRow + le * 16;
        float4 v[16];
        #pragma unroll
        for (int i = 0; i < 16; ++i) v[i] = s4p[i];

        float ss = 0.f;
        #pragma unroll
        for (int i = 0; i < 16; ++i)
            ss += v[i].x*v[i].x + v[i].y*v[i].y + v[i].z*v[i].z + v[i].w*v[i].w;
        // reduce across the 8-lane group (all 8 rows reduced simultaneously)
        ss += __shfl_xor(ss, 1);
        ss += __shfl_xor(ss, 2);
        ss += __shfl_xor(ss, 4);

        float n   = fmaxf(sqrtf(ss), 1e-15f);
        float arg = scc * n;
        float s   = __fdividef(fast_tanh_pos(arg), arg);   // expmap0 scale
        if (le == 0) sqv[rt] = s * s * ss;                 // ||mapped||^2 exactly

        #pragma unroll
        for (int i = 0; i < 8; ++i) {
            float4 a = v[2*i], b = v[2*i+1];
            s8v o;
            o[0]=(short)f2bf(a.x*s); o[1]=(short)f2bf(a.y*s);
            o[2]=(short)f2bf(a.z*s); o[3]=(short)f2bf(a.w*s);
            o[4]=(short)f2bf(b.x*s); o[5]=(short)f2bf(b.y*s);
            o[6]=(short)f2bf(b.z*s); o[7]=(short)f2bf(b.w*s);
            *(s8v*)(&dst[rt * LDK + le * 64 + i * 8]) = o;   // shorts: elems [le*64+8i, +8)
        }
    }

    __syncthreads();

    // ---- phase 2: split-K MFMA. wave = {quadrant q, K-half khalf} ----
    const int q     = w & 3;
    const int khalf = w >> 2;
    const int wr = q >> 1, wc = q & 1;
    const int rowA = 16 * wr + (lane & 15);
    const int rowB = 16 * wc + (lane & 15);
    const short* za = &zs[rowA * LDK + 8 * (lane >> 4) + khalf * 256];
    const short* pa = &ps[rowB * LDK + 8 * (lane >> 4) + khalf * 256];

    f4v acc = {0.f, 0.f, 0.f, 0.f};
    #pragma unroll
    for (int kk = 0; kk < 8; ++kk) {
        s8v af = *(const s8v*)(za + kk * 32);   // ds_read_b128
        s8v bf = *(const s8v*)(pa + kk * 32);
        acc = __builtin_amdgcn_mfma_f32_16x16x32_bf16(af, bf, acc, 0, 0, 0);
    }

    if (khalf) accbuf[q * 64 + lane] = acc;
    __syncthreads();

    if (!khalf) {
        acc += accbuf[q * 64 + lane];
        // C/D layout: col=lane&15, row=4*(lane>>4)+reg (m89-verified)
        const int col   = lane & 15;
        const int rbase = 4 * (lane >> 4);
        const int gcol  = col0 + 16 * wc + col;
        const float y2  = y2s[16 * wc + col];
        #pragma unroll
        for (int r = 0; r < 4; ++r) {
            int lrow = 16 * wr + rbase + r;
            float x2 = x2s[lrow];
            out[(size_t)(row0 + lrow) * C_ + gcol] = dist_val(acc[r], x2, y2, c, scc, inv_sc);
        }
    }
}

extern "C" void kernel_launch(void* const* d_in, const int* in_sizes, int n_in,
                              void* d_out, int out_size, void* d_ws, size_t ws_size,
                              hipStream_t stream) {
    const float* feats  = (const float*)d_in[0];
    const float* protos = (const float*)d_in[1];
    const float* raw_c  = (const float*)d_in[2];
    float* out = (float*)d_out;

    dim3 grid(C_ / 32, B_ / 32);
    fused_kernel<<<grid, 512, 0, stream>>>(feats, protos, raw_c, out);
}